// Round 12
// baseline (152.904 us; speedup 1.0000x reference)
//
#include <hip/hip_runtime.h>
#include <hip/hip_bf16.h>
#include <stdint.h>

#define NN 51200
#define FF 400
#define HH 256
#define CC 2
#define EE 819200
#define GG 128
#define NEG 0.01f
#define NKT 13          // ceil(400/32) K-tiles of 32
#define PAD 64          // padded neighbor slots per node
#define NBK 200         // dst buckets = dst>>8
#define EB  4096        // edges per block in sort passes (EE/NBK)
#define SLOT 8192       // ebuf slots per bucket (pow2)
#define TRS 264         // transpose tile row stride in shorts

typedef unsigned int u32;
typedef unsigned short u16;
typedef __attribute__((ext_vector_type(8))) short s8;    // 8 bf16
typedef __attribute__((ext_vector_type(4))) u32 u32x4;   // 16B vector
typedef __attribute__((ext_vector_type(2))) float f2;    // packed f32 pair
typedef __attribute__((ext_vector_type(4))) float f4;    // MFMA acc

__device__ __forceinline__ short f2bf(float f) {
    __hip_bfloat16 b = __float2bfloat16(f);
    return *reinterpret_cast<short*>(&b);
}
__device__ __forceinline__ float bflo(u32 x) { return __uint_as_float(x << 16); }
__device__ __forceinline__ float bfhi(u32 x) { return __uint_as_float(x & 0xffff0000u); }

// Order-preserving float<->uint encoding for atomicMax on floats.
__device__ __forceinline__ u32 encf(float f) {
    u32 u = __float_as_uint(f);
    return (u & 0x80000000u) ? ~u : (u | 0x80000000u);
}
__device__ __forceinline__ float decf(u32 e) {
    return (e & 0x80000000u) ? __uint_as_float(e & 0x7fffffffu)
                             : __uint_as_float(~e);
}

// ---- fused: place (blocks 0..NBK-1) + pack W (blocks NBK..NBK+51) +
//      penc/dummy-row init (block NBK+52) ----
__global__ __launch_bounds__(256) void k_placepack(
        const int* __restrict__ row, const int* __restrict__ col,
        int* __restrict__ cursor, u32* __restrict__ ebuf,
        const float* __restrict__ W, short* __restrict__ wp,
        short* __restrict__ h, u32* __restrict__ penc)
{
    const int b = blockIdx.x;
    const int t = threadIdx.x;
    if (b >= NBK) {
        const int pb = b - NBK;
        if (pb < 52) {                      // 52*256 = 13312 = NKT*16*64
            int g = pb * 256 + t;
            int l = g & 63;
            int k0 = (g >> 10) * 32 + ((l >> 4) * 8);
            int colw = ((g >> 6) & 15) * 16 + (l & 15);
            s8 v;
            #pragma unroll
            for (int j = 0; j < 8; ++j) {
                int k = k0 + j;
                v[j] = f2bf((k < FF) ? W[(size_t)k * HH + colw] : 0.f);
            }
            *(s8*)(wp + (size_t)g * 8) = v;
        } else {
            for (int i = t; i < GG * HH; i += 256) penc[i] = 0;
            if (t < 128) ((u32*)h)[(size_t)NN * 128 + t] = 0;  // dummy row
        }
        return;
    }
    __shared__ int lcnt[NBK], lbase[NBK];
    if (t < NBK) lcnt[t] = 0;
    __syncthreads();
    const int base = b * EB;
    for (int i = t; i < EB; i += 256)
        atomicAdd(&lcnt[col[base + i] >> 8], 1);
    __syncthreads();
    if (t < NBK) {
        int c = lcnt[t];
        if (c) lbase[t] = (t << 13) + atomicAdd(&cursor[t], c);
        lcnt[t] = 0;
    }
    __syncthreads();
    for (int i = t; i < EB; i += 256) {
        int d = col[base + i], s = row[base + i];
        int bb = d >> 8;
        int lp = atomicAdd(&lcnt[bb], 1);
        ebuf[lbase[bb] + lp] = ((u32)s << 8) | (u32)(d & 255);
    }
}

// ---- b2: one block per bucket, ELL slice in LDS, pads = 0xFFFF ----
__global__ __launch_bounds__(256) void k_b2(const u32* __restrict__ ebuf,
                                            const int* __restrict__ cursor,
                                            int* __restrict__ cnt,
                                            u16* __restrict__ csr) {
    __shared__ u16 ell[256 * PAD];     // 32 KB
    __shared__ int h[256];
    const int t = threadIdx.x;
    const int b = blockIdx.x;
    int* elli = (int*)ell;
    for (int i = t; i < 256 * PAD / 2; i += 256) elli[i] = -1;
    h[t] = 0;
    __syncthreads();
    int cb = cursor[b];
    cb = (cb < SLOT) ? cb : SLOT;
    const int ba = b << 13;
    for (int i = t; i < cb; i += 256) {
        u32 v = ebuf[ba + i];
        int dl = v & 255;
        int s = (int)(v >> 8);
        int p = atomicAdd(&h[dl], 1);
        if (p < PAD) ell[dl * PAD + p] = (u16)s;
    }
    __syncthreads();
    const int n0 = b << 8;
    cnt[n0 + t] = h[t];
    uint4* dst = (uint4*)(csr + (size_t)n0 * PAD);
    const uint4* src = (const uint4*)ell;
    for (int i = t; i < 256 * PAD * 2 / 16; i += 256) dst[i] = src[i];
}

// ---- MFMA GEMM v4 (unchanged control; measured this round) ----
__global__ __launch_bounds__(128) void k_mfma(
        const float* __restrict__ x, const short* __restrict__ wp,
        const int* __restrict__ cnt, short* __restrict__ h)
{
    __shared__ union {
        float As[2][2048];             // 16 KB staging (K-loop)
        short tr[16 * TRS];            // 8.25 KB transpose tile (epilogue)
    } sm;
    const int t = threadIdx.x;
    const int l = t & 63;
    const int w = t >> 6;              // wave 0/1
    const int bm = blockIdx.x * 64;
    const s8* wb = (const s8*)wp;

    const int rb = w * 32 + (l >> 3);             // + i*8, i=0..3
    const int sA = (l & 7) ^ ((l >> 3) & 7);      // swizzled source slot
    const size_t xmax = (size_t)NN * FF - 4;

    auto stage = [&](int kt, int buf) {
        #pragma unroll
        for (int i = 0; i < 4; ++i) {
            size_t idx = (size_t)(bm + rb + i * 8) * FF + sA * 4 + kt * 32;
            if (idx > xmax) idx = xmax;
            __builtin_amdgcn_global_load_lds(
                (const __attribute__((address_space(1))) void*)(x + idx),
                (__attribute__((address_space(3))) void*)(&sm.As[buf][(w * 4 + i) * 256]),
                16, 0, 0);
        }
    };

    f4 acc[4][8] = {};
    stage(0, 0);
    int buf = 0;
    const int s0 = (l >> 4) * 2;                  // first 16B slot of kl
    const int sx = l & 7;                         // == r&7 for the rows read
    for (int kt = 0; kt < NKT; ++kt) {
        __syncthreads();                          // stage(kt) landed
        if (kt + 1 < NKT) stage(kt + 1, buf ^ 1);
        s8 a[4];
        #pragma unroll
        for (int mi = 0; mi < 4; ++mi) {
            const int r = mi * 16 + (l & 15);     // r&7 == l&7 == sx
            float4 va = *(const float4*)&sm.As[buf][(r * 8 + (s0 ^ sx)) * 4];
            float4 vb = *(const float4*)&sm.As[buf][(r * 8 + ((s0 + 1) ^ sx)) * 4];
            a[mi][0] = f2bf(va.x); a[mi][1] = f2bf(va.y);
            a[mi][2] = f2bf(va.z); a[mi][3] = f2bf(va.w);
            a[mi][4] = f2bf(vb.x); a[mi][5] = f2bf(vb.y);
            a[mi][6] = f2bf(vb.z); a[mi][7] = f2bf(vb.w);
        }
        s8 b[8];
        #pragma unroll
        for (int ni = 0; ni < 8; ++ni)
            b[ni] = wb[(size_t)(kt * 16 + w * 8 + ni) * 64 + l];
        #pragma unroll
        for (int mi = 0; mi < 4; ++mi)
            #pragma unroll
            for (int ni = 0; ni < 8; ++ni)
                acc[mi][ni] = __builtin_amdgcn_mfma_f32_16x16x32_bf16(
                    a[mi], b[ni], acc[mi][ni], 0, 0, 0);
        buf ^= 1;
    }
    // ---- transpose epilogue ----
    #pragma unroll
    for (int mi = 0; mi < 4; ++mi) {
        __syncthreads();
        float dn[4];
        #pragma unroll
        for (int rr = 0; rr < 4; ++rr)
            dn[rr] = rsqrtf((float)(cnt[bm + mi * 16 + (l >> 4) * 4 + rr] + 1));
        #pragma unroll
        for (int ni = 0; ni < 8; ++ni) {
            const int col = w * 128 + ni * 16 + (l & 15);
            #pragma unroll
            for (int rr = 0; rr < 4; ++rr) {
                const int rloc = (l >> 4) * 4 + rr;
                sm.tr[rloc * TRS + col] = f2bf(dn[rr] * acc[mi][ni][rr]);
            }
        }
        __syncthreads();
        #pragma unroll
        for (int it = 0; it < 4; ++it) {
            const int r = it * 4 + (t >> 5);
            const int c0 = (t & 31) * 8;
            u32x4 v = *(const u32x4*)&sm.tr[r * TRS + c0];
            *(u32x4*)(h + (size_t)(bm + mi * 16 + r) * HH + c0) = v;
        }
    }
}

// ---- gather v4, now half-range (n0off) so top-5 shows k_mfma counters ----
__global__ __launch_bounds__(256) void k_gather(
        const short* __restrict__ h, const int* __restrict__ cnt,
        const u16* __restrict__ csr, const int* __restrict__ batch,
        const float* __restrict__ bg, u32* __restrict__ penc, int n0off)
{
    __shared__ f2 sM[256][4];      // 8 KB
    __shared__ int sB[256];
    const int t = threadIdx.x;
    const int l = t & 63;
    const int w = t >> 6;
    const int half = l >> 5, li = l & 31;
    const int ch0 = li * 8;
    const float4 b0 = *(const float4*)(bg + ch0);
    const float4 b1 = *(const float4*)(bg + ch0 + 4);

    f2 M[4];
    int runb = -1;
    const int nbase = n0off + blockIdx.x * 16 + w * 4;
    #pragma unroll
    for (int m = 0; m < 2; ++m) {
        const int n = nbase + m * 2 + half;
        const int degt = cnt[n];
        const int deg = (degt < PAD) ? degt : PAD;
        const float dn = rsqrtf((float)(degt + 1));
        const u16* cp = csr + (size_t)n * PAD;
        u32x4 sv = *(const u32x4*)(h + (size_t)n * HH + ch0);
        f2 a[4];
        a[0] = (f2){bflo(sv.x), bfhi(sv.x)};
        a[1] = (f2){bflo(sv.y), bfhi(sv.y)};
        a[2] = (f2){bflo(sv.z), bfhi(sv.z)};
        a[3] = (f2){bflo(sv.w), bfhi(sv.w)};
        int wmax = deg;
        wmax = max(wmax, __shfl_xor(wmax, 32, 64));
        u32x4 idx = *(const u32x4*)cp;
        for (int j0 = 0; j0 < wmax; j0 += 8) {
            u32x4 nxt = *(const u32x4*)(cp + j0 + 8);   // harmless overread
            #pragma unroll
            for (int k = 0; k < 8; ++k) {
                u32 ui = (idx[k >> 1] >> ((k & 1) * 16)) & 0xFFFFu;
                ui = (ui < (u32)NN) ? ui : (u32)NN;     // pad -> zero row
                u32x4 v = *(const u32x4*)(h + (size_t)ui * HH + ch0);
                a[0] += (f2){bflo(v.x), bfhi(v.x)};
                a[1] += (f2){bflo(v.y), bfhi(v.y)};
                a[2] += (f2){bflo(v.z), bfhi(v.z)};
                a[3] += (f2){bflo(v.w), bfhi(v.w)};
            }
            idx = nxt;
        }
        f2 val[4];
        val[0] = (f2){dn * a[0].x + b0.x, dn * a[0].y + b0.y};
        val[1] = (f2){dn * a[1].x + b0.z, dn * a[1].y + b0.w};
        val[2] = (f2){dn * a[2].x + b1.x, dn * a[2].y + b1.y};
        val[3] = (f2){dn * a[3].x + b1.z, dn * a[3].y + b1.w};
        #pragma unroll
        for (int q = 0; q < 4; ++q) {
            val[q].x = (val[q].x >= 0.f) ? val[q].x : NEG * val[q].x;
            val[q].y = (val[q].y >= 0.f) ? val[q].y : NEG * val[q].y;
        }
        const int b = batch[n];
        if (b != runb) {
            if (runb >= 0) {
                u32* p = penc + runb * HH + ch0;
                #pragma unroll
                for (int q = 0; q < 4; ++q) {
                    atomicMax(p + 2 * q, encf(M[q].x));
                    atomicMax(p + 2 * q + 1, encf(M[q].y));
                }
            }
            runb = b;
            #pragma unroll
            for (int q = 0; q < 4; ++q) M[q] = val[q];
        } else {
            #pragma unroll
            for (int q = 0; q < 4; ++q) {
                M[q].x = fmaxf(M[q].x, val[q].x);
                M[q].y = fmaxf(M[q].y, val[q].y);
            }
        }
    }
    #pragma unroll
    for (int q = 0; q < 4; ++q) sM[t][q] = M[q];
    sB[t] = runb;
    __syncthreads();
    if (t < 32) {
        int curb = sB[t];
        f2 cm[4];
        #pragma unroll
        for (int q = 0; q < 4; ++q) cm[q] = sM[t][q];
        #pragma unroll
        for (int s = 1; s < 8; ++s) {
            const int idx2 = s * 32 + t;
            const int bb = sB[idx2];
            if (bb == curb) {
                #pragma unroll
                for (int q = 0; q < 4; ++q) {
                    cm[q].x = fmaxf(cm[q].x, sM[idx2][q].x);
                    cm[q].y = fmaxf(cm[q].y, sM[idx2][q].y);
                }
            } else {
                u32* p = penc + curb * HH + t * 8;
                #pragma unroll
                for (int q = 0; q < 4; ++q) {
                    atomicMax(p + 2 * q, encf(cm[q].x));
                    atomicMax(p + 2 * q + 1, encf(cm[q].y));
                }
                curb = bb;
                #pragma unroll
                for (int q = 0; q < 4; ++q) cm[q] = sM[idx2][q];
            }
        }
        u32* p = penc + curb * HH + t * 8;
        #pragma unroll
        for (int q = 0; q < 4; ++q) {
            atomicMax(p + 2 * q, encf(cm[q].x));
            atomicMax(p + 2 * q + 1, encf(cm[q].y));
        }
    }
}

// ---- decode pool + write pool out + logits, one block per graph ----
__global__ __launch_bounds__(256) void k_out(
        const u32* __restrict__ penc, const float* __restrict__ Wl,
        const float* __restrict__ bl, float* __restrict__ out)
{
    __shared__ float r0[4], r1[4];
    const int g = blockIdx.x, t = threadIdx.x;
    float v = decf(penc[g * HH + t]);
    out[GG * CC + g * HH + t] = v;
    float s0 = v * Wl[t * CC + 0];
    float s1 = v * Wl[t * CC + 1];
    #pragma unroll
    for (int off = 32; off >= 1; off >>= 1) {
        s0 += __shfl_down(s0, off, 64);
        s1 += __shfl_down(s1, off, 64);
    }
    if ((t & 63) == 0) { r0[t >> 6] = s0; r1[t >> 6] = s1; }
    __syncthreads();
    if (t == 0) {
        out[g * CC + 0] = r0[0] + r0[1] + r0[2] + r0[3] + bl[0];
        out[g * CC + 1] = r1[0] + r1[1] + r1[2] + r1[3] + bl[1];
    }
}

extern "C" void kernel_launch(void* const* d_in, const int* in_sizes, int n_in,
                              void* d_out, int out_size, void* d_ws, size_t ws_size,
                              hipStream_t stream)
{
    const float* x    = (const float*)d_in[0];
    const int*   ei   = (const int*)d_in[1];
    const int*   batch= (const int*)d_in[2];
    const float* Wg   = (const float*)d_in[3];
    const float* bg   = (const float*)d_in[4];
    const float* Wl   = (const float*)d_in[5];
    const float* bl   = (const float*)d_in[6];
    float* out = (float*)d_out;
    const int* row = ei;        // sources
    const int* col = ei + EE;   // targets

    size_t o = 0;
    char* wsb = (char*)d_ws;
    auto take = [&](size_t b) { void* p = wsb + o; o += (b + 255) & ~(size_t)255; return p; };
    short* h    = (short*)take((size_t)(NN + 1) * HH * 2);            // 26.2 MB
    int*   cursor = (int*)take((size_t)NBK * 4);                      // 256B slot
    u32*   penc = (u32*)take((size_t)GG * HH * 4);
    int*   cnt  = (int*)take((size_t)NN * 4);
    u16*   csr  = (u16*)take((size_t)NN * PAD * 2);                   // 6.55 MB
    u32*   ebuf = (u32*)take((size_t)NBK * SLOT * 4);                 // 6.55 MB
    short* wp   = (short*)take((size_t)NKT * 16 * 64 * 8 * 2);        // 213 KB

    hipMemsetAsync(cursor, 0, (size_t)NBK * 4, stream);

    k_placepack<<<NBK + 53, 256, 0, stream>>>(row, col, cursor, ebuf,
                                              Wg, wp, h, penc);
    k_b2<<<NBK, 256, 0, stream>>>(ebuf, cursor, cnt, csr);
    k_mfma<<<NN / 64, 128, 0, stream>>>(x, wp, cnt, h);
    k_gather<<<NN / 32, 256, 0, stream>>>(h, cnt, csr, batch, bg, penc, 0);
    k_gather<<<NN / 32, 256, 0, stream>>>(h, cnt, csr, batch, bg, penc, NN / 2);
    k_out<<<GG, 256, 0, stream>>>(penc, Wl, bl, out);
}

// Round 13
// 133.808 us; speedup vs baseline: 1.1427x; 1.1427x over previous
//
#include <hip/hip_runtime.h>
#include <hip/hip_bf16.h>
#include <stdint.h>

#define NN 51200
#define FF 400
#define HH 256
#define CC 2
#define EE 819200
#define GG 128
#define NEG 0.01f
#define NKT 13          // ceil(400/32) K-tiles of 32
#define PAD 64          // padded neighbor slots per node
#define NBK 200         // dst buckets = dst>>8
#define EB  4096        // edges per block in sort passes (EE/NBK)
#define SLOT 8192       // ebuf slots per bucket (pow2)

typedef unsigned int u32;
typedef unsigned short u16;
typedef __attribute__((ext_vector_type(8))) short s8;    // 8 bf16
typedef __attribute__((ext_vector_type(4))) u32 u32x4;   // 16B vector
typedef __attribute__((ext_vector_type(2))) float f2;    // packed f32 pair
typedef __attribute__((ext_vector_type(4))) float f4;    // MFMA acc

__device__ __forceinline__ short f2bf(float f) {
    __hip_bfloat16 b = __float2bfloat16(f);
    return *reinterpret_cast<short*>(&b);
}
__device__ __forceinline__ float bflo(u32 x) { return __uint_as_float(x << 16); }
__device__ __forceinline__ float bfhi(u32 x) { return __uint_as_float(x & 0xffff0000u); }

// Order-preserving float<->uint encoding for atomicMax on floats.
__device__ __forceinline__ u32 encf(float f) {
    u32 u = __float_as_uint(f);
    return (u & 0x80000000u) ? ~u : (u | 0x80000000u);
}
__device__ __forceinline__ float decf(u32 e) {
    return (e & 0x80000000u) ? __uint_as_float(e & 0x7fffffffu)
                             : __uint_as_float(~e);
}

// ---- fused: place (blocks 0..NBK-1) + pack W (blocks NBK..NBK+51) +
//      penc/dummy-row init (block NBK+52) ----
__global__ __launch_bounds__(256) void k_placepack(
        const int* __restrict__ row, const int* __restrict__ col,
        int* __restrict__ cursor, u32* __restrict__ ebuf,
        const float* __restrict__ W, short* __restrict__ wp,
        short* __restrict__ h, u32* __restrict__ penc)
{
    const int b = blockIdx.x;
    const int t = threadIdx.x;
    if (b >= NBK) {
        const int pb = b - NBK;
        if (pb < 52) {                      // 52*256 = 13312 = NKT*16*64
            int g = pb * 256 + t;
            int l = g & 63;
            int k0 = (g >> 10) * 32 + ((l >> 4) * 8);
            int colw = ((g >> 6) & 15) * 16 + (l & 15);
            s8 v;
            #pragma unroll
            for (int j = 0; j < 8; ++j) {
                int k = k0 + j;
                v[j] = f2bf((k < FF) ? W[(size_t)k * HH + colw] : 0.f);
            }
            *(s8*)(wp + (size_t)g * 8) = v;
        } else {
            for (int i = t; i < GG * HH; i += 256) penc[i] = 0;
            if (t < 128) ((u32*)h)[(size_t)NN * 128 + t] = 0;  // dummy row
        }
        return;
    }
    __shared__ int lcnt[NBK], lbase[NBK];
    if (t < NBK) lcnt[t] = 0;
    __syncthreads();
    const int base = b * EB;
    for (int i = t; i < EB; i += 256)
        atomicAdd(&lcnt[col[base + i] >> 8], 1);
    __syncthreads();
    if (t < NBK) {
        int c = lcnt[t];
        if (c) lbase[t] = (t << 13) + atomicAdd(&cursor[t], c);
        lcnt[t] = 0;
    }
    __syncthreads();
    for (int i = t; i < EB; i += 256) {
        int d = col[base + i], s = row[base + i];
        int bb = d >> 8;
        int lp = atomicAdd(&lcnt[bb], 1);
        ebuf[lbase[bb] + lp] = ((u32)s << 8) | (u32)(d & 255);
    }
}

// ---- b2: one block per bucket, ELL slice in LDS, pads = 0xFFFF ----
__global__ __launch_bounds__(256) void k_b2(const u32* __restrict__ ebuf,
                                            const int* __restrict__ cursor,
                                            int* __restrict__ cnt,
                                            u16* __restrict__ csr) {
    __shared__ u16 ell[256 * PAD];     // 32 KB
    __shared__ int h[256];
    const int t = threadIdx.x;
    const int b = blockIdx.x;
    int* elli = (int*)ell;
    for (int i = t; i < 256 * PAD / 2; i += 256) elli[i] = -1;
    h[t] = 0;
    __syncthreads();
    int cb = cursor[b];
    cb = (cb < SLOT) ? cb : SLOT;
    const int ba = b << 13;
    for (int i = t; i < cb; i += 256) {
        u32 v = ebuf[ba + i];
        int dl = v & 255;
        int s = (int)(v >> 8);
        int p = atomicAdd(&h[dl], 1);
        if (p < PAD) ell[dl * PAD + p] = (u16)s;
    }
    __syncthreads();
    const int n0 = b << 8;
    cnt[n0 + t] = h[t];
    uint4* dst = (uint4*)(csr + (size_t)n0 * PAD);
    const uint4* src = (const uint4*)ell;
    for (int i = t; i < 256 * PAD * 2 / 16; i += 256) dst[i] = src[i];
}

// ---- MFMA GEMM v5: ring-3 LDS A, counted vmcnt (never 0), 1 barrier/kt ----
// 256 thr / 4 waves; BM=64, BN=256; wave w -> cols w*64..w*64+63, acc[4][4].
// Per kt per wave: 2 global_load_lds (A) + 4 reg B-loads = 6 counted VMEM.
__global__ __launch_bounds__(256) void k_mfma(
        const float* __restrict__ x, const short* __restrict__ wp,
        const int* __restrict__ cnt, short* __restrict__ h)
{
    __shared__ float As[3][2048];      // ring of 3 x 8 KB
    const int t = threadIdx.x;
    const int l = t & 63;
    const int w = t >> 6;              // wave 0..3
    const int bm = blockIdx.x * 64;
    const s8* wb = (const s8*)wp;

    // A staging: granule g = (w*2+i)*64 + l; row = g>>3, slot = l&7.
    // slot s stores source k-chunk s^(row&7); row&7 == l>>3 here.
    const int rowA = w * 16 + (l >> 3);           // + i*8
    const int csrc = (l & 7) ^ (l >> 3);          // source chunk for this slot
    auto stageA = [&](int kt, int buf) {
        #pragma unroll
        for (int i = 0; i < 2; ++i) {
            int k0 = kt * 32 + csrc * 4;
            if (k0 > FF - 4) k0 = FF - 4;         // k>=400 slots: B is 0 there
            const size_t idx = (size_t)(bm + rowA + i * 8) * FF + k0;
            __builtin_amdgcn_global_load_lds(
                (const __attribute__((address_space(1))) void*)(x + idx),
                (__attribute__((address_space(3))) void*)(&As[buf][(w * 2 + i) * 256]),
                16, 0, 0);
        }
    };
    auto loadB = [&](int kt, s8* b) {
        #pragma unroll
        for (int ni = 0; ni < 4; ++ni)
            b[ni] = wb[(size_t)(kt * 16 + w * 4 + ni) * 64 + l];
    };

    f4 acc[4][4] = {};
    stageA(0, 0);
    stageA(1, 1);
    s8 bcur[4], bnxt[4];
    loadB(0, bcur);
    const int s0 = (l >> 4) * 2;                  // first 16B k-chunk of lane
    const int sx = l & 7;                         // == row&7 for rows read
    for (int kt = 0; kt < NKT; ++kt) {
        // counted wait: A(kt) landed when <= (#loads issued after it) remain
        if (kt < NKT - 1) {
            asm volatile("s_waitcnt vmcnt(6)\n\ts_barrier" ::: "memory");
        } else {
            asm volatile("s_waitcnt vmcnt(4)\n\ts_barrier" ::: "memory");
        }
        if (kt + 2 < NKT) stageA(kt + 2, (kt + 2) % 3);   // overwrites buf kt-1
        if (kt + 1 < NKT) loadB(kt + 1, bnxt);
        const float* Ab = As[kt % 3];
        s8 a[4];
        #pragma unroll
        for (int mi = 0; mi < 4; ++mi) {
            const int r = mi * 16 + (l & 15);     // r&7 == l&7 == sx
            float4 va = *(const float4*)&Ab[(r * 8 + (s0 ^ sx)) * 4];
            float4 vb = *(const float4*)&Ab[(r * 8 + ((s0 + 1) ^ sx)) * 4];
            a[mi][0] = f2bf(va.x); a[mi][1] = f2bf(va.y);
            a[mi][2] = f2bf(va.z); a[mi][3] = f2bf(va.w);
            a[mi][4] = f2bf(vb.x); a[mi][5] = f2bf(vb.y);
            a[mi][6] = f2bf(vb.z); a[mi][7] = f2bf(vb.w);
        }
        #pragma unroll
        for (int mi = 0; mi < 4; ++mi)
            #pragma unroll
            for (int ni = 0; ni < 4; ++ni)
                acc[mi][ni] = __builtin_amdgcn_mfma_f32_16x16x32_bf16(
                    a[mi], bcur[ni], acc[mi][ni], 0, 0, 0);
        #pragma unroll
        for (int ni = 0; ni < 4; ++ni) bcur[ni] = bnxt[ni];
    }
    #pragma unroll
    for (int mi = 0; mi < 4; ++mi) {
        #pragma unroll
        for (int rr = 0; rr < 4; ++rr) {
            const int rowg = bm + mi * 16 + (l >> 4) * 4 + rr;
            const float dn = rsqrtf((float)(cnt[rowg] + 1));
            const size_t base = (size_t)rowg * HH + w * 64 + (l & 15);
            #pragma unroll
            for (int ni = 0; ni < 4; ++ni)
                h[base + ni * 16] = f2bf(dn * acc[mi][ni][rr]);
        }
    }
}

// ---- gather v4 (R11 best, single dispatch) ----
__global__ __launch_bounds__(256) void k_gather(
        const short* __restrict__ h, const int* __restrict__ cnt,
        const u16* __restrict__ csr, const int* __restrict__ batch,
        const float* __restrict__ bg, u32* __restrict__ penc)
{
    __shared__ f2 sM[256][4];      // 8 KB
    __shared__ int sB[256];
    const int t = threadIdx.x;
    const int l = t & 63;
    const int w = t >> 6;
    const int half = l >> 5, li = l & 31;
    const int ch0 = li * 8;
    const float4 b0 = *(const float4*)(bg + ch0);
    const float4 b1 = *(const float4*)(bg + ch0 + 4);

    f2 M[4];
    int runb = -1;
    const int nbase = blockIdx.x * 16 + w * 4;
    #pragma unroll
    for (int m = 0; m < 2; ++m) {
        const int n = nbase + m * 2 + half;
        const int degt = cnt[n];
        const int deg = (degt < PAD) ? degt : PAD;
        const float dn = rsqrtf((float)(degt + 1));
        const u16* cp = csr + (size_t)n * PAD;
        u32x4 sv = *(const u32x4*)(h + (size_t)n * HH + ch0);
        f2 a[4];
        a[0] = (f2){bflo(sv.x), bfhi(sv.x)};
        a[1] = (f2){bflo(sv.y), bfhi(sv.y)};
        a[2] = (f2){bflo(sv.z), bfhi(sv.z)};
        a[3] = (f2){bflo(sv.w), bfhi(sv.w)};
        int wmax = deg;
        wmax = max(wmax, __shfl_xor(wmax, 32, 64));
        u32x4 idx = *(const u32x4*)cp;
        for (int j0 = 0; j0 < wmax; j0 += 8) {
            u32x4 nxt = *(const u32x4*)(cp + j0 + 8);   // harmless overread
            #pragma unroll
            for (int k = 0; k < 8; ++k) {
                u32 ui = (idx[k >> 1] >> ((k & 1) * 16)) & 0xFFFFu;
                ui = (ui < (u32)NN) ? ui : (u32)NN;     // pad -> zero row
                u32x4 v = *(const u32x4*)(h + (size_t)ui * HH + ch0);
                a[0] += (f2){bflo(v.x), bfhi(v.x)};
                a[1] += (f2){bflo(v.y), bfhi(v.y)};
                a[2] += (f2){bflo(v.z), bfhi(v.z)};
                a[3] += (f2){bflo(v.w), bfhi(v.w)};
            }
            idx = nxt;
        }
        f2 val[4];
        val[0] = (f2){dn * a[0].x + b0.x, dn * a[0].y + b0.y};
        val[1] = (f2){dn * a[1].x + b0.z, dn * a[1].y + b0.w};
        val[2] = (f2){dn * a[2].x + b1.x, dn * a[2].y + b1.y};
        val[3] = (f2){dn * a[3].x + b1.z, dn * a[3].y + b1.w};
        #pragma unroll
        for (int q = 0; q < 4; ++q) {
            val[q].x = (val[q].x >= 0.f) ? val[q].x : NEG * val[q].x;
            val[q].y = (val[q].y >= 0.f) ? val[q].y : NEG * val[q].y;
        }
        const int b = batch[n];
        if (b != runb) {
            if (runb >= 0) {
                u32* p = penc + runb * HH + ch0;
                #pragma unroll
                for (int q = 0; q < 4; ++q) {
                    atomicMax(p + 2 * q, encf(M[q].x));
                    atomicMax(p + 2 * q + 1, encf(M[q].y));
                }
            }
            runb = b;
            #pragma unroll
            for (int q = 0; q < 4; ++q) M[q] = val[q];
        } else {
            #pragma unroll
            for (int q = 0; q < 4; ++q) {
                M[q].x = fmaxf(M[q].x, val[q].x);
                M[q].y = fmaxf(M[q].y, val[q].y);
            }
        }
    }
    #pragma unroll
    for (int q = 0; q < 4; ++q) sM[t][q] = M[q];
    sB[t] = runb;
    __syncthreads();
    if (t < 32) {
        int curb = sB[t];
        f2 cm[4];
        #pragma unroll
        for (int q = 0; q < 4; ++q) cm[q] = sM[t][q];
        #pragma unroll
        for (int s = 1; s < 8; ++s) {
            const int idx2 = s * 32 + t;
            const int bb = sB[idx2];
            if (bb == curb) {
                #pragma unroll
                for (int q = 0; q < 4; ++q) {
                    cm[q].x = fmaxf(cm[q].x, sM[idx2][q].x);
                    cm[q].y = fmaxf(cm[q].y, sM[idx2][q].y);
                }
            } else {
                u32* p = penc + curb * HH + t * 8;
                #pragma unroll
                for (int q = 0; q < 4; ++q) {
                    atomicMax(p + 2 * q, encf(cm[q].x));
                    atomicMax(p + 2 * q + 1, encf(cm[q].y));
                }
                curb = bb;
                #pragma unroll
                for (int q = 0; q < 4; ++q) cm[q] = sM[idx2][q];
            }
        }
        u32* p = penc + curb * HH + t * 8;
        #pragma unroll
        for (int q = 0; q < 4; ++q) {
            atomicMax(p + 2 * q, encf(cm[q].x));
            atomicMax(p + 2 * q + 1, encf(cm[q].y));
        }
    }
}

// ---- decode pool + write pool out + logits, one block per graph ----
__global__ __launch_bounds__(256) void k_out(
        const u32* __restrict__ penc, const float* __restrict__ Wl,
        const float* __restrict__ bl, float* __restrict__ out)
{
    __shared__ float r0[4], r1[4];
    const int g = blockIdx.x, t = threadIdx.x;
    float v = decf(penc[g * HH + t]);
    out[GG * CC + g * HH + t] = v;
    float s0 = v * Wl[t * CC + 0];
    float s1 = v * Wl[t * CC + 1];
    #pragma unroll
    for (int off = 32; off >= 1; off >>= 1) {
        s0 += __shfl_down(s0, off, 64);
        s1 += __shfl_down(s1, off, 64);
    }
    if ((t & 63) == 0) { r0[t >> 6] = s0; r1[t >> 6] = s1; }
    __syncthreads();
    if (t == 0) {
        out[g * CC + 0] = r0[0] + r0[1] + r0[2] + r0[3] + bl[0];
        out[g * CC + 1] = r1[0] + r1[1] + r1[2] + r1[3] + bl[1];
    }
}

extern "C" void kernel_launch(void* const* d_in, const int* in_sizes, int n_in,
                              void* d_out, int out_size, void* d_ws, size_t ws_size,
                              hipStream_t stream)
{
    const float* x    = (const float*)d_in[0];
    const int*   ei   = (const int*)d_in[1];
    const int*   batch= (const int*)d_in[2];
    const float* Wg   = (const float*)d_in[3];
    const float* bg   = (const float*)d_in[4];
    const float* Wl   = (const float*)d_in[5];
    const float* bl   = (const float*)d_in[6];
    float* out = (float*)d_out;
    const int* row = ei;        // sources
    const int* col = ei + EE;   // targets

    size_t o = 0;
    char* wsb = (char*)d_ws;
    auto take = [&](size_t b) { void* p = wsb + o; o += (b + 255) & ~(size_t)255; return p; };
    short* h    = (short*)take((size_t)(NN + 1) * HH * 2);            // 26.2 MB
    int*   cursor = (int*)take((size_t)NBK * 4);                      // 256B slot
    u32*   penc = (u32*)take((size_t)GG * HH * 4);
    int*   cnt  = (int*)take((size_t)NN * 4);
    u16*   csr  = (u16*)take((size_t)NN * PAD * 2);                   // 6.55 MB
    u32*   ebuf = (u32*)take((size_t)NBK * SLOT * 4);                 // 6.55 MB
    short* wp   = (short*)take((size_t)NKT * 16 * 64 * 8 * 2);        // 213 KB

    hipMemsetAsync(cursor, 0, (size_t)NBK * 4, stream);

    k_placepack<<<NBK + 53, 256, 0, stream>>>(row, col, cursor, ebuf,
                                              Wg, wp, h, penc);
    k_b2<<<NBK, 256, 0, stream>>>(ebuf, cursor, cnt, csr);
    k_mfma<<<NN / 64, 256, 0, stream>>>(x, wp, cnt, h);
    k_gather<<<NN / 16, 256, 0, stream>>>(h, cnt, csr, batch, bg, penc);
    k_out<<<GG, 256, 0, stream>>>(penc, Wl, bl, out);
}